// Round 7
// baseline (9272.027 us; speedup 1.0000x reference)
//
#include <hip/hip_runtime.h>

// ---------------------------------------------------------------------------
// Persistent-kernel Seq2Seq LSTM, cross-XCD dataflow via SYSTEM-scope atomics.
// R14 = R13 + XCD-LOCAL A-STAGING (attack the 50 MB/step uncached A-traffic).
//  - New WG map: XCD x hosts n in {2x..2x+3} (weights 1.6MB/XCD, L2-resident)
//    and m in {x&1 ? 8..15 : 0..7}; the 4 WGs sharing (x,m) form a group.
//  - Group leader (j==0) sys-copies A (h-slices) once into a per-group staging
//    buffer (plain stores -> own L2), publishes monotonic agent-scope counter;
//    followers poll (sc0, L2-local) and read A via sc0 loads (bypass L1, hit
//    L2). 16x -> 4x amplification: ~50 -> ~12 MB/step of fabric traffic.
//  - Physical-XCD check via s_getreg(HW_REG_XCC_ID): follower uses staging
//    ONLY if leader is physically co-located (published xcc map); else falls
//    back to the proven direct system-load path. Correctness never assumes
//    bid->XCD placement.
//  - A-loads widened to global_load_dwordx4 (sc0 sc1 / sc0 inline asm).
//  - Flags, bumps, readback-validate, epilogue: identical to R13.
// ---------------------------------------------------------------------------

typedef _Float16 half_t;
typedef _Float16 half8 __attribute__((ext_vector_type(8)));
typedef float floatx4 __attribute__((ext_vector_type(4)));
typedef unsigned long long u64;
typedef u64 u64x2 __attribute__((ext_vector_type(2)));

#define B_ 1024
#define S_ 256
#define IN_ 64
#define H_ 512
#define NT_ 8
#define HOR_ 24
#define NG_ 2048       // 4*H
#define BH_ (B_ * H_)
// flag index: each (slot,m) flag padded to its own 128B line (32 ints)
#define FIDX(s, mm) ((((s) * 16) + (mm)) << 5)
#define STG0_SZ (64 * 512)     // halves per L0 staging slot (64 KB)
#define STG1_SZ (64 * 1024)    // halves per L1 staging slot (128 KB)

__device__ __forceinline__ void async_cp16(const void* g, void* l) {
  __builtin_amdgcn_global_load_lds((const __attribute__((address_space(1))) void*)g,
                                   (__attribute__((address_space(3))) void*)l,
                                   16, 0, 0);
}

__device__ __forceinline__ float fast_sig(float x) {
  return __builtin_amdgcn_rcpf(1.0f + __builtin_amdgcn_exp2f(-1.44269504f * x));
}
__device__ __forceinline__ float fast_tanh(float x) {
  float xx = fminf(10.0f, fmaxf(-10.0f, x));
  float e = __builtin_amdgcn_exp2f(2.88539008f * xx);
  return (e - 1.0f) * __builtin_amdgcn_rcpf(e + 1.0f);
}

// SYSTEM-scope relaxed atomics (sc0 sc1; bypass L2, IF-coherent)
__device__ __forceinline__ u64 sys_ld8(const void* p) {
  return __hip_atomic_load((const u64*)p, __ATOMIC_RELAXED, __HIP_MEMORY_SCOPE_SYSTEM);
}
__device__ __forceinline__ unsigned sys_ld4(const void* p) {
  return __hip_atomic_load((const unsigned*)p, __ATOMIC_RELAXED, __HIP_MEMORY_SCOPE_SYSTEM);
}
__device__ __forceinline__ void sys_st8(void* p, u64 v) {
  __hip_atomic_store((u64*)p, v, __ATOMIC_RELAXED, __HIP_MEMORY_SCOPE_SYSTEM);
}
__device__ __forceinline__ void sys_st4(void* p, unsigned v) {
  __hip_atomic_store((unsigned*)p, v, __ATOMIC_RELAXED, __HIP_MEMORY_SCOPE_SYSTEM);
}
// 16B cache-bypassing loads (untracked asm: consume only after vmwait0 or
// __syncthreads, both of which drain vmcnt(0))
__device__ __forceinline__ u64x2 ld16_sys(const void* p) {   // system: IF
  u64x2 r;
  asm volatile("global_load_dwordx4 %0, %1, off sc0 sc1" : "=v"(r) : "v"(p));
  return r;
}
__device__ __forceinline__ u64x2 ld16_sc0(const void* p) {   // agent: L2
  u64x2 r;
  asm volatile("global_load_dwordx4 %0, %1, off sc0" : "=v"(r) : "v"(p));
  return r;
}
__device__ __forceinline__ void vmwait0() {
  asm volatile("s_waitcnt vmcnt(0)" ::: "memory");
}
__device__ __forceinline__ int get_xcc() {
  int x;
  asm volatile("s_getreg_b32 %0, hwreg(HW_REG_XCC_ID)" : "=s"(x));
  return x & 7;
}
// tid0-only spin; compiler fence at exit blocks hoisting of later ops.
__device__ __forceinline__ void wait_ge(const int* f, int tgt) {
  while (__hip_atomic_load(f, __ATOMIC_RELAXED, __HIP_MEMORY_SCOPE_SYSTEM) < tgt)
    __builtin_amdgcn_s_sleep(1);
  asm volatile("" ::: "memory");
}
__device__ __forceinline__ void bump(int* f) {
  asm volatile("" ::: "memory");
  __hip_atomic_fetch_add(f, 1, __ATOMIC_RELAXED, __HIP_MEMORY_SCOPE_SYSTEM);
  asm volatile("" ::: "memory");
}

// ---------------- setup kernels ----------------

__global__ void k_xT(const float* __restrict__ x, half_t* __restrict__ xf) {
  int i = blockIdx.x * 256 + threadIdx.x;  // (t*B + b)*64 + e
  int e = i & 63;
  int tb = i >> 6;
  int t = tb >> 10;
  int b = tb & 1023;
  xf[i] = (half_t)x[((size_t)b * S_ + t) * 64 + e];
}

__global__ void k_pack(const float* __restrict__ Wih, const float* __restrict__ Whh,
                       const float* __restrict__ bias,
                       half_t* __restrict__ Wp, float* __restrict__ bp,
                       int K0real, int K0pad, int K) {
  int i = blockIdx.x * 256 + threadIdx.x;
  if (i >= NG_ * K) return;
  int r = i / K;
  int k = i - r * K;
  int j = r >> 2, g = r & 3;
  int src = g * H_ + j;
  float v;
  if (k < K0pad) v = (k < K0real) ? Wih[src * K0real + k] : 0.0f;
  else           v = Whh[src * H_ + (k - K0pad)];
  Wp[i] = (half_t)v;
  if (k == 0) bp[r] = bias[src];
}

__global__ void k_init(half_t* h0, half_t* h1, half_t* dpad,
                       int* fh0, int* fh1, int* ffc, int* rdy, int* xccmap) {
  int i = blockIdx.x * 256 + threadIdx.x;
  if (i < BH_) {
    h0[i] = (half_t)0.0f; h0[i + BH_] = (half_t)0.0f; h0[i + 2 * BH_] = (half_t)0.0f;
    h1[i] = (half_t)0.0f; h1[i + BH_] = (half_t)0.0f; h1[i + 2 * BH_] = (half_t)0.0f;
  }
  if (i < B_ * 64) dpad[i] = (half_t)0.0f;
  if (i < 384 * 16) {                      // (slot,m) pairs; slots 0,1 preset
    int v = (i < 32) ? 16 : 0;
    fh0[i << 5] = v; fh1[i << 5] = v;
  }
  if (i < 32 * 16) ffc[i << 5] = 0;
  if (i < 128) rdy[i << 5] = 0;
  if (i < 512) xccmap[i << 5] = -1;
}

// ---------------- fused GEMM + LSTM-cell (device) ----------------
// WG tile 64(M) x 128(N gates), 4 waves, wave tile 32x64. BK=64 chunks,
// double-buffered LDS. B (weights): global_load_lds from warm L2.
// A: 16B loads (SC0A: agent/L2 from staging; else system/IF direct)
//    -> regs (pipelined) -> ds_write_b128.

template <bool SC0A>
__device__ __forceinline__ void gemm_cell(
    half_t* ldsA, half_t* ldsB, half_t* ldsH, bool mode0, bool sysA0,
    const half_t* s0, int str0, const half_t* sA, const half_t* sB,
    const half_t* __restrict__ Bs, int K, int NC,
    const float* __restrict__ bp, float* creg,
    half_t* __restrict__ hout, int M0, int N0) {
  const int tid = threadIdx.x;
  const int l = tid & 63, w = tid >> 6;
  const int wm = w >> 1, wn = w & 1;
  const int fr = l & 15, q = l >> 4;
  const int r8 = l >> 3, c8 = l & 7;

  floatx4 acc[2][4];
#pragma unroll
  for (int a = 0; a < 2; ++a)
#pragma unroll
    for (int b = 0; b < 4; ++b) acc[a][b] = (floatx4){0.f, 0.f, 0.f, 0.f};

  auto issue_A = [&](int c, u64x2 (&ar)[2]) {
    const half_t* base; int str; int flavor;   // 0 plain, 1 sys, 2 A-path
    if (mode0) {
      if (c == 0) { base = s0; str = str0; flavor = sysA0 ? 1 : 0; }
      else        { base = sA + (size_t)(c - 1) * 64; str = H_; flavor = 2; }
    } else {
      base = (c < 8) ? sA + (size_t)c * 64 : sB + (size_t)(c - 8) * 64;
      str = H_; flavor = 2;
    }
#pragma unroll
    for (int ii = 0; ii < 2; ++ii) {
      int i = 2 * w + ii;
      int r = 8 * i + r8;
      int sc = c8 ^ r8;
      const half_t* p = base + (size_t)r * str + sc * 8;
      if (flavor == 0)      ar[ii] = *(const u64x2*)p;
      else if (flavor == 1) ar[ii] = ld16_sys(p);
      else                  ar[ii] = SC0A ? ld16_sc0(p) : ld16_sys(p);
    }
  };
  auto write_A = [&](int buf, u64x2 (&ar)[2]) {
    half_t* la = ldsA + buf * 4096;
#pragma unroll
    for (int ii = 0; ii < 2; ++ii) {
      int i = 2 * w + ii;
      *(u64x2*)(la + i * 512 + 64 * r8 + 8 * c8) = ar[ii];   // ds_write_b128
    }
  };
  auto stage_B = [&](int c, int buf) {
    half_t* lb = ldsB + buf * 8192;
    const half_t* bsrc = Bs + (size_t)c * 64;
#pragma unroll
    for (int jj = 0; jj < 4; ++jj) {
      int j = 4 * w + jj;
      int r = 8 * j + r8;
      int sc = c8 ^ r8;
      async_cp16(bsrc + (size_t)r * K + sc * 8, lb + j * 512);
    }
  };

  u64x2 ar[2][2];
  issue_A(0, ar[0]);
  vmwait0();             // asm loads are untracked: explicit drain before use
  write_A(0, ar[0]);
  stage_B(0, 0);
  issue_A(1, ar[1]);
  int buf = 0;
  for (int c = 0; c < NC; ++c) {
    __syncthreads();     // vmcnt(0) drain: buf B staged, prefetched A in regs
    if (c + 2 < NC) issue_A(c + 2, ar[c & 1]);   // ar[c&1] free (chunk c in LDS)
    if (c + 1 < NC) {
      write_A(buf ^ 1, ar[(c + 1) & 1]);
      stage_B(c + 1, buf ^ 1);
    }
    const half_t* la = ldsA + buf * 4096;
    const half_t* lb = ldsB + buf * 8192;
#pragma unroll
    for (int kk = 0; kk < 2; ++kk) {
      half8 av[2], bv[4];
#pragma unroll
      for (int mt = 0; mt < 2; ++mt) {
        int r = wm * 32 + mt * 16 + fr;
        int sc = (4 * kk + q) ^ (fr & 7);
        av[mt] = *(const half8*)(la + r * 64 + sc * 8);
      }
#pragma unroll
      for (int nt = 0; nt < 4; ++nt) {
        int r = wn * 64 + nt * 16 + fr;
        int sc = (4 * kk + q) ^ (fr & 7);
        bv[nt] = *(const half8*)(lb + r * 64 + sc * 8);
      }
#pragma unroll
      for (int mt = 0; mt < 2; ++mt)
#pragma unroll
        for (int nt = 0; nt < 4; ++nt)
          acc[mt][nt] = __builtin_amdgcn_mfma_f32_16x16x32_f16(av[mt], bv[nt], acc[mt][nt], 0, 0, 0);
    }
    buf ^= 1;
  }

  // epilogue: bias + (i,f,g,o) shfl-gather + register-resident cell update;
  // h via dedicated ldsH, then wide system-scope stores + readback-validate.
  const int base = l & ~3;
  const int gsel = l & 3;
#pragma unroll
  for (int nt = 0; nt < 4; ++nt) {
    const int ncl = wn * 64 + nt * 16 + fr;   // local gate col
    const float bc = bp[N0 + ncl];
    const int lc = ncl >> 2;                  // local cell col 0..31
#pragma unroll
    for (int mt = 0; mt < 2; ++mt) {
      const float csnap = creg[nt * 2 + mt];  // pre-update snapshot
#pragma unroll
      for (int r = 0; r < 4; ++r) {
        float v = acc[mt][nt][r] + bc;
        float gi = __shfl(v, base + 0);
        float gf = __shfl(v, base + 1);
        float gg = __shfl(v, base + 2);
        float go = __shfl(v, base + 3);
        float cold = __shfl(csnap, base + r); // keeper lane gsel==r
        const float cn = fast_sig(gf) * cold + fast_sig(gi) * fast_tanh(gg);
        const float hn = fast_sig(go) * fast_tanh(cn);
        if (gsel == r) creg[nt * 2 + mt] = cn;
        if (gsel == 0) {
          const int lm = wm * 32 + mt * 16 + q * 4 + r;
          ldsH[lm * 32 + lc] = (half_t)hn;
        }
      }
    }
  }
  __syncthreads();
  {
    const int tr = tid >> 2, cg = tid & 3;
    const u64* lp = (const u64*)(ldsH + tr * 32 + cg * 8);
    half_t* dst = hout + (size_t)(M0 + tr) * H_ + (N0 >> 2) + cg * 8;
    sys_st8(dst, lp[0]);
    sys_st8(dst + 4, lp[1]);
    // readback-validate: per-address ordering => load response implies the
    // store is visible at the coherence point. Keep values live (no DCE).
    u64 ca = sys_ld8(dst);
    u64 cb = sys_ld8(dst + 4);
    asm volatile("" :: "v"(ca), "v"(cb));
  }
}

// ---------------- the persistent kernel ----------------
// 512 WGs. wtype = bid>>8. New map: x=bid&7 (assumed XCD), idx=(bid&255)>>3,
// j=idx&3, mm=idx>>2; n=(2x+j)&15, m=mm+8*(x&1). Group (x,wtype,mm) = 4 WGs
// sharing one A-slice; j==0 is leader (stages A), j>0 followers (sc0-read)
// when physically co-located with leader (xccmap check), else direct sys.
//
// Flag protocol (slot = step+2; slots 0,1 preset; 128B-padded lines):
//   fh0[FIDX(slot,m)]==16 <=> h0(slot-2) done;  fh1 likewise;  ffc[t,m]>=1.
//   L0(u): fh0[u+1], fh1[u-1] (WAR), ffc[t-1].
//   L1(u): fh0[u+2], fh1[u+1], ffc[u-S-3].   FC(t): fh1[u+2].
// Staging WAR safety: leader at u overwrites parity slot of u-2; its waits
// (fh0[u+1] / fh1[u+1]) imply step u-1 group done => u-2 done (monotone).

__global__ __launch_bounds__(256, 2)
void k_seq(const half_t* __restrict__ xf,
           const half_t* __restrict__ Wp0e, const float* __restrict__ bp0e,
           const half_t* __restrict__ Wp1e, const float* __restrict__ bp1e,
           const half_t* __restrict__ Wp0d, const float* __restrict__ bp0d,
           const half_t* __restrict__ Wp1d, const float* __restrict__ bp1d,
           half_t* __restrict__ h0, half_t* __restrict__ h1,
           half_t* __restrict__ dpad,
           const float* __restrict__ Wfc, const float* __restrict__ bfc,
           float* __restrict__ out,
           int* __restrict__ fh0, int* __restrict__ fh1, int* __restrict__ ffc,
           half_t* __restrict__ stg0, half_t* __restrict__ stg1,
           int* __restrict__ rdy, int* __restrict__ xccmap) {
  __shared__ __align__(16) half_t ldsA[2 * 64 * 64];    // 16 KB
  __shared__ __align__(16) half_t ldsB[2 * 128 * 64];   // 32 KB
  __shared__ __align__(16) half_t ldsH[64 * 32];        // 4 KB (dedicated)
  __shared__ int s_flag;

  const int tid = threadIdx.x;
  const int bid = blockIdx.x;
  const int wtype = bid >> 8;          // 0: L0 worker, 1: L1 worker
  const int b8 = bid & 255;
  const int x   = b8 & 7;              // assumed XCD
  const int idx = b8 >> 3;             // 0..31
  const int j   = idx & 3;
  const int mm  = idx >> 2;            // 0..7
  const int n   = (2 * x + j) & 15;
  const int m   = mm + 8 * (x & 1);
  const int M0 = m * 64, N0 = n * 128;
  const bool leader = (j == 0);
  const int leader_bid = wtype * 256 + x + 32 * mm;
  const int slotbase = x * 8 + mm;     // 0..63
  int* rdyp = rdy + ((wtype * 64 + slotbase) << 5);

  half_t* h0s[3] = {h0, h0 + BH_, h0 + 2 * BH_};
  half_t* h1s[3] = {h1, h1 + BH_, h1 + 2 * BH_};

  // publish own physical XCD; followers check leader co-location once.
  const int phys = get_xcc();
  if (tid == 0) {
    sys_st4(xccmap + (bid << 5), (unsigned)phys);
    unsigned rb = sys_ld4(xccmap + (bid << 5));   // readback-validate
    asm volatile("" :: "v"(rb));
  }
  bool useStage = true;
  if (!leader) {
    if (tid == 0) {
      unsigned lx;
      while ((lx = sys_ld4(xccmap + (leader_bid << 5))) == 0xFFFFFFFFu)
        __builtin_amdgcn_s_sleep(1);
      s_flag = (lx == (unsigned)phys) ? 1 : 0;
    }
    __syncthreads();
    useStage = (s_flag != 0);
    asm volatile("" ::: "memory");
  }

  // leader copy: rounds16 x 4KB, 8 loads in flight then drain then store.
  auto copy_rounds = [&](const half_t* __restrict__ src, half_t* __restrict__ dst) {
    for (int g = 0; g < 16; g += 8) {
      u64x2 v[8];
#pragma unroll
      for (int i2 = 0; i2 < 8; ++i2) {
        int off = ((g + i2) * 256 + tid) * 8;
        v[i2] = ld16_sys(src + off);
      }
      vmwait0();
#pragma unroll
      for (int i2 = 0; i2 < 8; ++i2) {
        int off = ((g + i2) * 256 + tid) * 8;
        *((u64x2*)(dst + off)) = v[i2];
      }
    }
  };

  float cr[8];
#pragma unroll
  for (int i = 0; i < 8; ++i) cr[i] = 0.0f;

  if (wtype == 0) {
    // -------- L0 chain: h0(u) = cell(x(u)|dpad(t), h0(u-1)) --------
    for (int u = 0; u < S_ + HOR_; ++u) {
      const bool dec = (u >= S_);
      const int t = u - S_;
      if (tid == 0) {
        wait_ge(fh0 + FIDX(u + 1, m), 16);               // h0(u-1)
        if (u >= 1) wait_ge(fh1 + FIDX(u - 1, m), 16);   // h0 slot back-pressure
        if (dec && t >= 1) wait_ge(ffc + FIDX(t - 1, m), 1);  // dpad(t)
      }
      __syncthreads();
      asm volatile("" ::: "memory");
      const int scur = u % 3, sp = (u + 2) % 3;
      const half_t* s0 = dec ? (dpad + (size_t)M0 * 64)
                             : (xf + ((size_t)u * B_ + M0) * 64);
      const half_t* srcA = h0s[sp] + (size_t)M0 * H_;
      const half_t* W = (dec ? Wp0d : Wp0e) + (size_t)N0 * 576;
      const float* bpp = dec ? bp0d : bp0e;
      half_t* stgA = stg0 + (size_t)((u & 1) * 64 + slotbase) * STG0_SZ;
      if (leader) {
        copy_rounds(srcA, stgA);
        __syncthreads();                                 // all waves' stores in L2
        if (tid == 0)
          __hip_atomic_store(rdyp, u + 1, __ATOMIC_RELAXED, __HIP_MEMORY_SCOPE_AGENT);
        gemm_cell<true>(ldsA, ldsB, ldsH, true, dec, s0, 64,
                        stgA, (const half_t*)0, W, 576, 9, bpp, cr, h0s[scur], M0, N0);
      } else if (useStage) {
        if (tid == 0) {
          while (__hip_atomic_load(rdyp, __ATOMIC_RELAXED, __HIP_MEMORY_SCOPE_AGENT) < u + 1)
            __builtin_amdgcn_s_sleep(1);
        }
        __syncthreads();
        asm volatile("" ::: "memory");
        gemm_cell<true>(ldsA, ldsB, ldsH, true, dec, s0, 64,
                        stgA, (const half_t*)0, W, 576, 9, bpp, cr, h0s[scur], M0, N0);
      } else {
        gemm_cell<false>(ldsA, ldsB, ldsH, true, dec, s0, 64,
                         srcA, (const half_t*)0, W, 576, 9, bpp, cr, h0s[scur], M0, N0);
      }
      __syncthreads();                                   // all readbacks done
      if (tid == 0) bump(fh0 + FIDX(u + 2, m));
    }
  } else {
    // -------- L1 chain: h1(u) = cell(h0(u), h1(u-1)); + FC in decoder --------
    for (int u = 0; u < S_ + HOR_; ++u) {
      const bool dec = (u >= S_);
      const int t = u - S_;
      if (tid == 0) {
        wait_ge(fh0 + FIDX(u + 2, m), 16);               // h0(u)
        wait_ge(fh1 + FIDX(u + 1, m), 16);               // h1(u-1)
        if (u >= S_ + 3) wait_ge(ffc + FIDX(u - S_ - 3, m), 1);  // FC done w/ h1(u-3)
      }
      __syncthreads();
      asm volatile("" ::: "memory");
      const int scur = u % 3, sp = (u + 2) % 3;
      const half_t* srcA = h0s[scur] + (size_t)M0 * H_;
      const half_t* srcB = h1s[sp] + (size_t)M0 * H_;
      const half_t* W = (dec ? Wp1d : Wp1e) + (size_t)N0 * 1024;
      const float* bpp = dec ? bp1d : bp1e;
      half_t* stgA = stg1 + (size_t)((u & 1) * 64 + slotbase) * STG1_SZ;
      half_t* stgB = stgA + 64 * 512;
      if (leader) {
        copy_rounds(srcA, stgA);
        copy_rounds(srcB, stgB);
        __syncthreads();
        if (tid == 0)
          __hip_atomic_store(rdyp, u + 1, __ATOMIC_RELAXED, __HIP_MEMORY_SCOPE_AGENT);
        gemm_cell<true>(ldsA, ldsB, ldsH, false, false, (const half_t*)0, 0,
                        stgA, stgB, W, 1024, 16, bpp, cr, h1s[scur], M0, N0);
      } else if (useStage) {
        if (tid == 0) {
          while (__hip_atomic_load(rdyp, __ATOMIC_RELAXED, __HIP_MEMORY_SCOPE_AGENT) < u + 1)
            __builtin_amdgcn_s_sleep(1);
        }
        __syncthreads();
        asm volatile("" ::: "memory");
        gemm_cell<true>(ldsA, ldsB, ldsH, false, false, (const half_t*)0, 0,
                        stgA, stgB, W, 1024, 16, bpp, cr, h1s[scur], M0, N0);
      } else {
        gemm_cell<false>(ldsA, ldsB, ldsH, false, false, (const half_t*)0, 0,
                         srcA, srcB, W, 1024, 16, bpp, cr, h1s[scur], M0, N0);
      }
      __syncthreads();
      if (tid == 0) bump(fh1 + FIDX(u + 2, m));
      if (dec && n == 0) {                               // WG (m, L1, n=0): FC + feedback
        if (tid == 0) wait_ge(fh1 + FIDX(u + 2, m), 16);
        __syncthreads();
        asm volatile("" ::: "memory");
        for (int half = 0; half < 2; ++half) {
          // stage 32 h1 rows (32 KB) into ldsB via system loads
#pragma unroll
          for (int i = 0; i < 16; ++i) {
            int li = tid * 16 + i;                 // 0..4095
            int rr = li >> 7, ee = li & 127;       // row 0..31, 8B-chunk 0..127
            ((u64*)ldsB)[li] =
                sys_ld8(h1s[scur] + (size_t)(M0 + half * 32 + rr) * H_ + ee * 4);
          }
          __syncthreads();
          const int r = tid >> 3, cc = tid & 7;
          const int rowg = M0 + half * 32 + r;
          const half_t* hl = ldsB + r * 512;
          const float* wr = Wfc + cc * H_;
          float s = bfc[cc];
#pragma unroll 8
          for (int k8 = 0; k8 < H_ / 8; ++k8) {
            half8 hv = *(const half8*)(hl + k8 * 8);
#pragma unroll
            for (int e = 0; e < 8; ++e) s += (float)hv[e] * wr[k8 * 8 + e];
          }
          out[((size_t)rowg * HOR_ + t) * NT_ + cc] = s;
          float sn = __shfl(s, (tid & 63) + 1);          // pair-neighbor
          if (!(cc & 1)) {
            half_t* dp = dpad + rowg * 64 + cc;
            unsigned pk = (unsigned)__builtin_bit_cast(unsigned short, (half_t)s)
                        | ((unsigned)__builtin_bit_cast(unsigned short, (half_t)sn) << 16);
            sys_st4(dp, pk);
            unsigned ck = sys_ld4(dp);                   // readback-validate
            asm volatile("" :: "v"(ck));
          }
          __syncthreads();
        }
        if (tid == 0) bump(ffc + FIDX(t, m));
      }
    }
  }
}

// ---------------- host ----------------

extern "C" void kernel_launch(void* const* d_in, const int* in_sizes, int n_in,
                              void* d_out, int out_size, void* d_ws, size_t ws_size,
                              hipStream_t stream) {
  (void)in_sizes; (void)n_in; (void)out_size; (void)ws_size;
  const float* x     = (const float*)d_in[0];
  const float* Wih0e = (const float*)d_in[1];
  const float* Whh0e = (const float*)d_in[2];
  const float* b0e   = (const float*)d_in[3];
  const float* Wih1e = (const float*)d_in[4];
  const float* Whh1e = (const float*)d_in[5];
  const float* b1e   = (const float*)d_in[6];
  const float* Wih0d = (const float*)d_in[7];
  const float* Whh0d = (const float*)d_in[8];
  const float* b0d   = (const float*)d_in[9];
  const float* Wih1d = (const float*)d_in[10];
  const float* Whh1d = (const float*)d_in[11];
  const float* b1d   = (const float*)d_in[12];
  const float* Wfc   = (const float*)d_in[13];
  const float* bfc   = (const float*)d_in[14];
  float* out = (float*)d_out;

  char* p = (char*)d_ws;
  auto alloc = [&](size_t bytes) {
    char* r = p;
    p += (bytes + 255) & ~(size_t)255;
    return r;
  };
  half_t* xf   = (half_t*)alloc((size_t)S_ * B_ * 64 * 2);
  half_t* Wp0e = (half_t*)alloc((size_t)NG_ * 576 * 2);
  half_t* Wp1e = (half_t*)alloc((size_t)NG_ * 1024 * 2);
  half_t* Wp0d = (half_t*)alloc((size_t)NG_ * 576 * 2);
  half_t* Wp1d = (half_t*)alloc((size_t)NG_ * 1024 * 2);
  float*  bp0e = (float*)alloc(NG_ * 4);
  float*  bp1e = (float*)alloc(NG_ * 4);
  float*  bp0d = (float*)alloc(NG_ * 4);
  float*  bp1d = (float*)alloc(NG_ * 4);
  half_t* h0   = (half_t*)alloc((size_t)3 * BH_ * 2);
  half_t* h1   = (half_t*)alloc((size_t)3 * BH_ * 2);
  half_t* dpad = (half_t*)alloc((size_t)B_ * 64 * 2);
  int*    fh0  = (int*)alloc((size_t)384 * 16 * 32 * 4);   // padded flags
  int*    fh1  = (int*)alloc((size_t)384 * 16 * 32 * 4);
  int*    ffc  = (int*)alloc((size_t)32 * 16 * 32 * 4);
  half_t* stg0 = (half_t*)alloc((size_t)2 * 64 * STG0_SZ * 2);  // 8 MB
  half_t* stg1 = (half_t*)alloc((size_t)2 * 64 * STG1_SZ * 2);  // 16 MB
  int*    rdy  = (int*)alloc((size_t)128 * 32 * 4);
  int*    xccm = (int*)alloc((size_t)512 * 32 * 4);

  k_xT<<<(S_ * B_ * 64) / 256, 256, 0, stream>>>(x, xf);
  k_pack<<<(NG_ * 576) / 256, 256, 0, stream>>>(Wih0e, Whh0e, b0e, Wp0e, bp0e, 64, 64, 576);
  k_pack<<<(NG_ * 1024) / 256, 256, 0, stream>>>(Wih1e, Whh1e, b1e, Wp1e, bp1e, 512, 512, 1024);
  k_pack<<<(NG_ * 576) / 256, 256, 0, stream>>>(Wih0d, Whh0d, b0d, Wp0d, bp0d, 8, 64, 576);
  k_pack<<<(NG_ * 1024) / 256, 256, 0, stream>>>(Wih1d, Whh1d, b1d, Wp1d, bp1d, 512, 512, 1024);
  k_init<<<BH_ / 256, 256, 0, stream>>>(h0, h1, dpad, fh0, fh1, ffc, rdy, xccm);

  k_seq<<<512, 256, 0, stream>>>(xf, Wp0e, bp0e, Wp1e, bp1e, Wp0d, bp0d, Wp1d, bp1d,
                                 h0, h1, dpad, Wfc, bfc, out, fh0, fh1, ffc,
                                 stg0, stg1, rdy, xccm);
}